// Round 1
// baseline (450.008 us; speedup 1.0000x reference)
//
#include <hip/hip_runtime.h>

// Forward-fill (LOCF) along L for x:(B,L,N) fp32, NaN = missing.
// Outputs: x_filled (B*L*N fp32) then mask as 0.0/1.0 fp32, concatenated in d_out.
//
// Three-phase chunked scan:
//   k_tail : per (b, chunk, n) last observed value in chunk (NaN if none)
//   k_carry: sequential scan over chunks per (b, n) -> carry-in per chunk
//   k_fill : per-chunk forward fill starting from carry; writes out + mask

constexpr int B = 32, L = 4096, N = 256;
constexpr int N4 = N / 4;   // float4 granularity across channels
constexpr int CPB = 4;      // chunks per 256-thread block (64 lanes per chunk)

__device__ __forceinline__ float dev_nan() { return __int_as_float(0x7fc00000); }

template <int LC>
__global__ __launch_bounds__(256) void k_tail(const float4* __restrict__ x4,
                                              float4* __restrict__ tail4) {
    constexpr int C = L / LC;
    const int gid   = blockIdx.x;
    const int b     = gid / (C / CPB);
    const int cgrp  = gid % (C / CPB);
    const int chunk = cgrp * CPB + (threadIdx.x >> 6);
    const int n4    = threadIdx.x & 63;

    const float4* p = x4 + (long)(b * L + chunk * LC) * N4 + n4;
    float lx = dev_nan(), ly = dev_nan(), lz = dev_nan(), lw = dev_nan();
#pragma unroll 4
    for (int i = 0; i < LC; ++i) {
        float4 v = p[(long)i * N4];
        if (v.x == v.x) lx = v.x;
        if (v.y == v.y) ly = v.y;
        if (v.z == v.z) lz = v.z;
        if (v.w == v.w) lw = v.w;
    }
    tail4[(long)(b * C + chunk) * N4 + n4] = make_float4(lx, ly, lz, lw);
}

template <int LC>
__global__ __launch_bounds__(256) void k_carry(const float4* __restrict__ tail4,
                                               float4* __restrict__ carry4) {
    constexpr int C = L / LC;
    const int t = blockIdx.x * blockDim.x + threadIdx.x;  // 0 .. B*N4-1
    if (t >= B * N4) return;
    const int b  = t / N4;
    const int n4 = t % N4;

    float cx = dev_nan(), cy = dev_nan(), cz = dev_nan(), cw = dev_nan();
    for (int c = 0; c < C; ++c) {
        const long idx = (long)(b * C + c) * N4 + n4;
        carry4[idx] = make_float4(cx, cy, cz, cw);
        float4 v = tail4[idx];
        if (v.x == v.x) cx = v.x;
        if (v.y == v.y) cy = v.y;
        if (v.z == v.z) cz = v.z;
        if (v.w == v.w) cw = v.w;
    }
}

template <int LC>
__global__ __launch_bounds__(256) void k_fill(const float4* __restrict__ x4,
                                              const float4* __restrict__ carry4,
                                              float4* __restrict__ out4,
                                              float4* __restrict__ m4) {
    constexpr int C = L / LC;
    const int gid   = blockIdx.x;
    const int b     = gid / (C / CPB);
    const int cgrp  = gid % (C / CPB);
    const int chunk = cgrp * CPB + (threadIdx.x >> 6);
    const int n4    = threadIdx.x & 63;

    const long base = (long)(b * L + chunk * LC) * N4 + n4;
    float4 last = carry4[(long)(b * C + chunk) * N4 + n4];

#pragma unroll 4
    for (int i = 0; i < LC; ++i) {
        const long idx = base + (long)i * N4;
        float4 v = x4[idx];
        const bool ox = (v.x == v.x);
        const bool oy = (v.y == v.y);
        const bool oz = (v.z == v.z);
        const bool ow = (v.w == v.w);
        if (ox) last.x = v.x;
        if (oy) last.y = v.y;
        if (oz) last.z = v.z;
        if (ow) last.w = v.w;
        float4 o;
        o.x = (last.x == last.x) ? last.x : 0.0f;
        o.y = (last.y == last.y) ? last.y : 0.0f;
        o.z = (last.z == last.z) ? last.z : 0.0f;
        o.w = (last.w == last.w) ? last.w : 0.0f;
        out4[idx] = o;
        if (m4) {
            m4[idx] = make_float4(ox ? 1.0f : 0.0f, oy ? 1.0f : 0.0f,
                                  oz ? 1.0f : 0.0f, ow ? 1.0f : 0.0f);
        }
    }
}

template <int LC>
static void run_all(const float* x, float* out, float* mask_out, void* d_ws,
                    hipStream_t stream) {
    constexpr int C = L / LC;
    float* tail  = (float*)d_ws;
    float* carry = tail + (long)B * C * N;
    k_tail<LC><<<B * C / CPB, 256, 0, stream>>>((const float4*)x, (float4*)tail);
    k_carry<LC><<<(B * N4 + 255) / 256, 256, 0, stream>>>((const float4*)tail,
                                                          (float4*)carry);
    k_fill<LC><<<B * C / CPB, 256, 0, stream>>>((const float4*)x,
                                                (const float4*)carry,
                                                (float4*)out, (float4*)mask_out);
}

extern "C" void kernel_launch(void* const* d_in, const int* in_sizes, int n_in,
                              void* d_out, int out_size, void* d_ws, size_t ws_size,
                              hipStream_t stream) {
    const float* x = (const float*)d_in[0];
    const long n_total = (long)B * L * N;  // 33,554,432

    float* out = (float*)d_out;
    float* mask_out = ((long)out_size >= 2 * n_total) ? out + n_total : nullptr;

    // LC=32 (C=128) needs 2 * B*C*N * 4 B = 8 MiB of workspace; fall back to
    // LC=128 (C=32, 2 MiB) if the workspace is small.
    if (ws_size >= 2ull * B * (L / 32) * N * sizeof(float)) {
        run_all<32>(x, out, mask_out, d_ws, stream);
    } else {
        run_all<128>(x, out, mask_out, d_ws, stream);
    }
}